// Round 11
// baseline (7956.458 us; speedup 1.0000x reference)
//
#include <hip/hip_runtime.h>

// R5 CHAMPION, RESUBMITTED VERBATIM (R11 = A/A reproducibility check).
// R7-R10 variants (butterfly, per-wave epilogue, swizzled hstage, sleep,
// 4-chain) all measured 7.9-10.9 ms vs this kernel's 6.78 ms; this run
// decides champion-real (~6.8) vs bench-noise (~7.5-8.0) worlds.

#define TS    2048
#define BTOT  32
#define IDIM  256
#define HDIM  512
#define GRPS  8      // batch groups (4 batches each); WGs of a group exchange h only within the group
#define WPG   32     // WGs per group: 64 gate cols each (16 h-cols x 4 gates)
#define BPG   4
#define NTHR  256    // 4 waves; wave wv = gate wv (N-split, full K)
#define KX    8      // x k-frags (K=256)
#define KT    24     // + 16 h k-frags (K=512)
#define SROW  520    // LDS h-stage row stride in shorts (512 + 8 pad: bank-shifts rows)

typedef __attribute__((ext_vector_type(8))) short    bfrag;  // 8 bf16
typedef __attribute__((ext_vector_type(4))) float    facc;   // 4 f32
typedef unsigned long long u64;

#define LD_A64(p)   __hip_atomic_load((p),  __ATOMIC_RELAXED, __HIP_MEMORY_SCOPE_AGENT)
#define ST_A64(p,v) __hip_atomic_store((p),(v),__ATOMIC_RELAXED, __HIP_MEMORY_SCOPE_AGENT)

__device__ __forceinline__ unsigned short f2bf(float f){
    unsigned u = __builtin_bit_cast(unsigned, f);
    u += 0x7FFFu + ((u >> 16) & 1u);            // RNE
    return (unsigned short)(u >> 16);
}
__device__ __forceinline__ unsigned pack2(float a, float b){
    return (unsigned)f2bf(a) | ((unsigned)f2bf(b) << 16);
}

// Protocol (R3-proven primitives, group-local volume):
//  - hgrp = hbuf + g*2048: [2 parity][1024] u64 words; word W of parity p holds
//    h-cols {2W%512, +1} of batch W>>8 (group-local), tag = step+1 in high 32.
//  - h(s) lives in parity s&1 with tag s+1. Consumer at step t retries until
//    all its 4 words carry tag t+1. Data+tag move atomically: NO ordering
//    assumptions, no fences, no sc bits, placement-independent.
//  - Overwrite safety: h(t+2) lands in parity t&1 only after all group WGs
//    published h(t+1), which requires their reads of h(t) to have completed.
//  - x is register-resident bf16, prefetched 2 steps ahead (off critical path).
//  - out stores AFTER the publish (host-only data).
#define LSTM_STEP(Tt, XF, TPF)                                                              \
  do {                                                                                      \
    facc ze = {0.f,0.f,0.f,0.f}, zo = {0.f,0.f,0.f,0.f};                                    \
    _Pragma("unroll")                                                                       \
    for (int j = 0; j < KX; j += 2){                                                        \
      ze = __builtin_amdgcn_mfma_f32_16x16x32_bf16(XF[j],   breg[j],   ze, 0,0,0);          \
      zo = __builtin_amdgcn_mfma_f32_16x16x32_bf16(XF[j+1], breg[j+1], zo, 0,0,0);          \
    }                                                                                       \
    const unsigned want = (unsigned)(Tt) + 1u;                                              \
    while ((((unsigned)(w0 >> 32) != want) | ((unsigned)(w1 >> 32) != want) |               \
            ((unsigned)(w2 >> 32) != want) | ((unsigned)(w3 >> 32) != want)) != 0u){        \
      if ((unsigned)(w0 >> 32) != want) w0 = LD_A64(hsrc + 0);                              \
      if ((unsigned)(w1 >> 32) != want) w1 = LD_A64(hsrc + 1);                              \
      if ((unsigned)(w2 >> 32) != want) w2 = LD_A64(hsrc + 2);                              \
      if ((unsigned)(w3 >> 32) != want) w3 = LD_A64(hsrc + 3);                              \
    }                                                                                       \
    { uint4 pv; pv.x = (unsigned)w0; pv.y = (unsigned)w1;                                   \
      pv.z = (unsigned)w2; pv.w = (unsigned)w3;                                             \
      *reinterpret_cast<uint4*>(                                                            \
          reinterpret_cast<char*>(hstage) + sb * (SROW*2) + sw * 4) = pv; }                 \
    __syncthreads();                                  /* B1: h staged */                    \
    _Pragma("unroll")                                                                       \
    for (int j = 0; j < 16; j += 2){                                                        \
      const bfrag ha = *reinterpret_cast<const bfrag*>(&hstage[lb*SROW + j*32 + kgrp*8]);   \
      const bfrag hb = *reinterpret_cast<const bfrag*>(&hstage[lb*SROW + (j+1)*32 + kgrp*8]); \
      ze = __builtin_amdgcn_mfma_f32_16x16x32_bf16(ha, breg[KX+j],   ze, 0,0,0);            \
      zo = __builtin_amdgcn_mfma_f32_16x16x32_bf16(hb, breg[KX+j+1], zo, 0,0,0);            \
    }                                                                                       \
    const facc zz = ze + zo;                                                                \
    if (lane < 16){   /* D rows 0..3 = batches (rows 4..15 junk, never read) */             \
      _Pragma("unroll")                                                                     \
      for (int q = 0; q < 4; ++q) zfull[wv][q][lane] = zz[q];                               \
    }                                                                                       \
    __syncthreads();                                  /* B2: z ready */                     \
    float hn0 = 0.f, hn1 = 0.f;                                                             \
    if (gth){                                                                               \
      float zg0[4], zg1[4];                                                                 \
      _Pragma("unroll")                                                                     \
      for (int gt = 0; gt < 4; ++gt){                                                       \
        zg0[gt] = zfull[gt][b][col0]     + bs2[gt][0] + wt2[gt][0] * (TPF);                 \
        zg1[gt] = zfull[gt][b][col0 + 1] + bs2[gt][1] + wt2[gt][1] * (TPF);                 \
      }                                                                                     \
      { const float ig = 1.f/(1.f+__expf(-zg0[0]));                                         \
        const float fg = 1.f/(1.f+__expf(-zg0[1]));                                         \
        const float gg = 1.f - 2.f/(__expf(2.f*zg0[2])+1.f);                                \
        const float og = 1.f/(1.f+__expf(-zg0[3]));                                         \
        creg0 = fg*creg0 + ig*gg;                                                           \
        hn0 = og*(1.f - 2.f/(__expf(2.f*creg0)+1.f)); }                                     \
      { const float ig = 1.f/(1.f+__expf(-zg1[0]));                                         \
        const float fg = 1.f/(1.f+__expf(-zg1[1]));                                         \
        const float gg = 1.f - 2.f/(__expf(2.f*zg1[2])+1.f);                                \
        const float og = 1.f/(1.f+__expf(-zg1[3]));                                         \
        creg1 = fg*creg1 + ig*gg;                                                           \
        hn1 = og*(1.f - 2.f/(__expf(2.f*creg1)+1.f)); }                                     \
      ST_A64(hgrp + (size_t)(((Tt)+1) & 1) * 1024 + b*256 + r*8 + cp,                       \
             ((u64)((unsigned)(Tt) + 2u) << 32) | (u64)pack2(hn0, hn1));                    \
    }                                                                                       \
    /* ---- tail: off critical path ---- */                                                 \
    { const int tn = ((Tt)+2 < TS) ? ((Tt)+2) : (TS-1);                                     \
      hsrc = hgrp + (size_t)(((Tt) + 1) & 1) * 1024 + (size_t)tid * 4;                      \
      w0 = LD_A64(hsrc + 0); w1 = LD_A64(hsrc + 1);                                         \
      w2 = LD_A64(hsrc + 2); w3 = LD_A64(hsrc + 3);                                         \
      if (ldr){                                                                             \
        _Pragma("unroll")                                                                   \
        for (int j = 0; j < KX; ++j){                                                       \
          const float4* p4 = reinterpret_cast<const float4*>(                               \
              x + ((size_t)tn*BTOT + lbg)*IDIM + j*32 + kgrp*8);                            \
          const float4 f0 = p4[0], f1 = p4[1];                                              \
          bfrag v;                                                                          \
          v[0]=(short)f2bf(f0.x); v[1]=(short)f2bf(f0.y);                                   \
          v[2]=(short)f2bf(f0.z); v[3]=(short)f2bf(f0.w);                                   \
          v[4]=(short)f2bf(f1.x); v[5]=(short)f2bf(f1.y);                                   \
          v[6]=(short)f2bf(f1.z); v[7]=(short)f2bf(f1.w);                                   \
          XF[j] = v;                                                                        \
        }                                                                                   \
      }                                                                                     \
      if (gth){                                                                             \
        (TPF) = tim[(size_t)tn*BTOT + bglob];                                               \
        *reinterpret_cast<float2*>(                                                         \
            &out[((size_t)(Tt)*BTOT + bglob)*HDIM + hcol0]) = make_float2(hn0, hn1);        \
        if ((Tt) == TS-1){                                                                  \
          float* hT = out + (size_t)TS*BTOT*HDIM;                                           \
          float* cT = hT + (size_t)BTOT*HDIM;                                               \
          *reinterpret_cast<float2*>(&hT[(size_t)bglob*HDIM + hcol0]) = make_float2(hn0, hn1); \
          *reinterpret_cast<float2*>(&cT[(size_t)bglob*HDIM + hcol0]) = make_float2(creg0, creg1); \
        }                                                                                   \
      }                                                                                     \
    }                                                                                       \
  } while(0)

__global__ __launch_bounds__(NTHR, 1) void lstm_grp(
    const float* __restrict__ x,      // [T,B,I]
    const float* __restrict__ tim,    // [T,B,1]
    const float* __restrict__ Wih,    // [4H, I+1]
    const float* __restrict__ Whh,    // [4H, H]
    const float* __restrict__ bias,   // [4H]
    const float* __restrict__ h0,     // [B,H]
    const float* __restrict__ c0,     // [B,H]
    float* __restrict__ out,          // [T,B,H] ++ [B,H] ++ [B,H]
    u64* __restrict__ hbuf)           // [GRPS][2][1024] tagged words
{
    const int tid = threadIdx.x, bid = blockIdx.x;
    const int g = bid & 7, r = bid >> 3;           // group, role (16 h-cols r*16..)
    const int wv = tid >> 6, lane = tid & 63, l15 = lane & 15, kgrp = lane >> 4;

    __shared__ unsigned short hstage[BPG * SROW];  // 4.1 KB: h rows [4][520]
    __shared__ float zfull[4][4][16];              // [gate][b][col]

    u64* hgrp = hbuf + (size_t)g * 2048;

    // ---- weights in registers: wave wv = gate wv, cols r*16+l15, full K ----
    bfrag breg[KT];
    {
        const int colg = wv * HDIM + r * 16 + l15;
        #pragma unroll
        for (int j = 0; j < KT; ++j){
            const float* src = (j < KX)
                ? (Wih + (size_t)colg * (IDIM + 1) + j * 32 + kgrp * 8)
                : (Whh + (size_t)colg * HDIM + (j - KX) * 32 + kgrp * 8);
            bfrag v;
            #pragma unroll
            for (int q = 0; q < 8; ++q) v[q] = (short)f2bf(src[q]);
            breg[j] = v;
        }
    }

    // ---- gate threads (tid<32): item (b, col0=2*cp, col0+1) ----
    const bool gth = (tid < 32);
    const int b = (tid >> 3) & 3, cp = tid & 7, col0 = cp * 2;
    const int hcol0 = r * 16 + col0, bglob = g * BPG + b;
    float bs2[4][2], wt2[4][2];
    float creg0 = 0.f, creg1 = 0.f;
    if (gth){
        #pragma unroll
        for (int gt = 0; gt < 4; ++gt){
            const size_t cg = (size_t)gt * HDIM + hcol0;
            bs2[gt][0] = bias[cg];     bs2[gt][1] = bias[cg + 1];
            wt2[gt][0] = Wih[cg * (IDIM + 1) + IDIM];
            wt2[gt][1] = Wih[(cg + 1) * (IDIM + 1) + IDIM];
        }
        creg0 = c0[(size_t)bglob * HDIM + hcol0];
        creg1 = c0[(size_t)bglob * HDIM + hcol0 + 1];
        // publish h(0): parity 0, tag 1
        ST_A64(hgrp + 0 * 1024 + b * 256 + r * 8 + cp,
               (1ULL << 32) | (u64)pack2(h0[(size_t)bglob * HDIM + hcol0],
                                         h0[(size_t)bglob * HDIM + hcol0 + 1]));
    } else {
        #pragma unroll
        for (int gt = 0; gt < 4; ++gt){
            bs2[gt][0] = bs2[gt][1] = wt2[gt][0] = wt2[gt][1] = 0.f;
        }
    }

    // ---- consumer stage indices: thread stages words tid*4..tid*4+3 ----
    const int sb = (tid * 4) >> 8;          // batch row 0..3
    const int sw = (tid * 4) & 255;         // word within row

    // ---- A-loader lanes: row = batch lb (MFMA rows 4..15 junk) ----
    const bool ldr = (l15 < 4);
    const int lb = l15 & 3;
    const int lbg = g * BPG + lb;

    // ---- x prefetch: x(0)->xe, x(1)->xo (bf16, registers) ----
    bfrag xe[KX], xo[KX];
    #pragma unroll
    for (int j = 0; j < KX; ++j){
        bfrag zv;
        #pragma unroll
        for (int q = 0; q < 8; ++q) zv[q] = 0;
        xe[j] = zv; xo[j] = zv;
    }
    if (ldr){
        #pragma unroll
        for (int j = 0; j < KX; ++j){
            const float4* p0 = reinterpret_cast<const float4*>(
                x + ((size_t)0 * BTOT + lbg) * IDIM + j * 32 + kgrp * 8);
            const float4* p1 = reinterpret_cast<const float4*>(
                x + ((size_t)1 * BTOT + lbg) * IDIM + j * 32 + kgrp * 8);
            const float4 a0 = p0[0], a1 = p0[1], b0 = p1[0], b1 = p1[1];
            bfrag v;
            v[0]=(short)f2bf(a0.x); v[1]=(short)f2bf(a0.y);
            v[2]=(short)f2bf(a0.z); v[3]=(short)f2bf(a0.w);
            v[4]=(short)f2bf(a1.x); v[5]=(short)f2bf(a1.y);
            v[6]=(short)f2bf(a1.z); v[7]=(short)f2bf(a1.w);
            xe[j] = v;
            bfrag w;
            w[0]=(short)f2bf(b0.x); w[1]=(short)f2bf(b0.y);
            w[2]=(short)f2bf(b0.z); w[3]=(short)f2bf(b0.w);
            w[4]=(short)f2bf(b1.x); w[5]=(short)f2bf(b1.y);
            w[6]=(short)f2bf(b1.z); w[7]=(short)f2bf(b1.w);
            xo[j] = w;
        }
    }
    float tpe = 0.f, tpo = 0.f;
    if (gth){
        tpe = tim[(size_t)0 * BTOT + bglob];
        tpo = tim[(size_t)1 * BTOT + bglob];
    }

    // ---- issue initial tagged loads (parity 0) ----
    const u64* hsrc = hgrp + (size_t)tid * 4;
    u64 w0 = LD_A64(hsrc + 0), w1 = LD_A64(hsrc + 1);
    u64 w2 = LD_A64(hsrc + 2), w3 = LD_A64(hsrc + 3);

    for (int t = 0; t < TS; t += 2){
        LSTM_STEP(t,     xe, tpe);
        LSTM_STEP(t + 1, xo, tpo);
    }
}

extern "C" void kernel_launch(void* const* d_in, const int* in_sizes, int n_in,
                              void* d_out, int out_size, void* d_ws, size_t ws_size,
                              hipStream_t stream) {
    const float* x    = (const float*)d_in[0];
    const float* tim  = (const float*)d_in[1];
    const float* Wih  = (const float*)d_in[2];
    const float* Whh  = (const float*)d_in[3];
    const float* bias = (const float*)d_in[4];
    const float* h0   = (const float*)d_in[5];
    const float* c0   = (const float*)d_in[6];

    u64* hbuf = (u64*)d_ws;

    // tags must start != any wanted tag every launch (graph replays included)
    hipMemsetAsync(d_ws, 0, GRPS * 2 * 1024 * sizeof(u64), stream);

    lstm_grp<<<GRPS * WPG, NTHR, 0, stream>>>(x, tim, Wih, Whh, bias, h0, c0,
                                              (float*)d_out, hbuf);
}